// Round 1
// baseline (432.525 us; speedup 1.0000x reference)
//
#include <hip/hip_runtime.h>
#include <hip/hip_bf16.h>

typedef unsigned short u16;
typedef unsigned int   u32;
typedef __bf16 bf16x8 __attribute__((ext_vector_type(8)));
typedef float  f32x4  __attribute__((ext_vector_type(4)));
typedef u16    u16x8  __attribute__((ext_vector_type(8)));

#define GAS __attribute__((address_space(1)))
#define LAS __attribute__((address_space(3)))

__device__ __forceinline__ void gload_lds16(const void* g, void* lds) {
  __builtin_amdgcn_global_load_lds((GAS u32*)g, (LAS u32*)lds, 16, 0, 0);
}

__device__ __forceinline__ u16 f2bf(float f) {
  union { float f; u32 u; } v; v.f = f;
  u32 r = v.u + 0x7FFFu + ((v.u >> 16) & 1u);   // round-to-nearest-even
  return (u16)(r >> 16);
}

// ---------------- elementwise cast x: f32 -> bf16 (8 elems/thread) ----------------
__global__ __launch_bounds__(256) void cast_x_kernel(const float* __restrict__ x,
                                                     u16* __restrict__ xb) {
  int i = (blockIdx.x * 256 + threadIdx.x) * 8;
  float4 a = *(const float4*)(x + i);
  float4 b = *(const float4*)(x + i + 4);
  u16x8 o;
  o[0] = f2bf(a.x); o[1] = f2bf(a.y); o[2] = f2bf(a.z); o[3] = f2bf(a.w);
  o[4] = f2bf(b.x); o[5] = f2bf(b.y); o[6] = f2bf(b.z); o[7] = f2bf(b.w);
  *(u16x8*)(xb + i) = o;
}

// ---------------- transpose-cast: W[k][n] f32 -> WT[n][k] bf16 ----------------
__global__ __launch_bounds__(256) void transcast(const float* __restrict__ W,
                                                 u16* __restrict__ WT, int dim) {
  __shared__ float t[32][33];
  int tx = threadIdx.x, ty = threadIdx.y;      // 32 x 8
  int c0 = blockIdx.x * 32, r0 = blockIdx.y * 32;
#pragma unroll
  for (int i = 0; i < 4; ++i)
    t[ty + i * 8][tx] = W[(r0 + ty + i * 8) * dim + c0 + tx];
  __syncthreads();
#pragma unroll
  for (int i = 0; i < 4; ++i)
    WT[(c0 + ty + i * 8) * dim + r0 + tx] = f2bf(t[tx][ty + i * 8]);
}

// ---------------- GEMM: C[M][N] = A[M][K] * B^T (B stored [N][K]) ----------------
// 128x128 tile, BK=32, 4 waves (2x2), each wave 64x64 (4x4 frags of 16x16).
// LDS staged via global_load_lds w16, XOR swizzle q^=(row>>1)&3 (pre-swizzled src).
template <int OUTF32>
__global__ __launch_bounds__(256) void gemm_bt(
    const u16* __restrict__ A, const u16* __restrict__ B,
    float* __restrict__ Cf, u16* __restrict__ Cb, const float* __restrict__ bias,
    int M, int N, int K, int lda, int ldb, int ldc) {
  __shared__ alignas(16) u16 As[128 * 32];
  __shared__ alignas(16) u16 Bs[128 * 32];
  const int tid = threadIdx.x;
  const int lane = tid & 63, wave = tid >> 6;
  const int wm = wave >> 1, wn = wave & 1;
  const int r15 = lane & 15, g = lane >> 4;
  const int tm = blockIdx.x * 128, tn = blockIdx.y * 128;

  // staging: 512 chunks of 16B per tile; thread handles 2 (rounds i*4+wave)
  int aoff[2], boff[2], sbase[2];
#pragma unroll
  for (int i = 0; i < 2; ++i) {
    int c = (i * 4 + wave) * 64 + lane;       // 0..511
    int row = c >> 2;                          // 4 chunks per 32-elem row
    int q = (c & 3) ^ ((row >> 1) & 3);        // inverse-swizzled source chunk
    aoff[i] = (tm + row) * lda + q * 8;
    boff[i] = (tn + row) * ldb + q * 8;
    sbase[i] = (i * 4 + wave) * 1024;          // bytes
  }
  // fragment read offsets (bytes), swizzled
  const int sw = (r15 >> 1) & 3;
  int ard[4], brd[4];
#pragma unroll
  for (int t = 0; t < 4; ++t) {
    ard[t] = (wm * 64 + t * 16 + r15) * 64 + ((g ^ sw) << 4);
    brd[t] = (wn * 64 + t * 16 + r15) * 64 + ((g ^ sw) << 4);
  }

  f32x4 acc[4][4] = {};

  for (int k0 = 0; k0 < K; k0 += 32) {
    __syncthreads();
#pragma unroll
    for (int i = 0; i < 2; ++i) {
      gload_lds16(A + aoff[i] + k0, (char*)As + sbase[i]);
      gload_lds16(B + boff[i] + k0, (char*)Bs + sbase[i]);
    }
    __syncthreads();
    bf16x8 af[4], bfr[4];
#pragma unroll
    for (int t = 0; t < 4; ++t) {
      af[t]  = *(const bf16x8*)((const char*)As + ard[t]);
      bfr[t] = *(const bf16x8*)((const char*)Bs + brd[t]);
    }
#pragma unroll
    for (int mi = 0; mi < 4; ++mi)
#pragma unroll
      for (int ni = 0; ni < 4; ++ni)
        acc[mi][ni] = __builtin_amdgcn_mfma_f32_16x16x32_bf16(af[mi], bfr[ni],
                                                              acc[mi][ni], 0, 0, 0);
  }

#pragma unroll
  for (int mi = 0; mi < 4; ++mi)
#pragma unroll
    for (int ni = 0; ni < 4; ++ni)
#pragma unroll
      for (int r = 0; r < 4; ++r) {
        int m = tm + wm * 64 + mi * 16 + g * 4 + r;
        int n = tn + wn * 64 + ni * 16 + r15;
        float v = acc[mi][ni][r];
        if (OUTF32) Cf[m * ldc + n] = v + bias[n];
        else        Cb[m * ldc + n] = f2bf(v);
      }
}

// ---------------- flash attention ----------------
// QKV: [B*S][6144] bf16 rows = {Q[h][d], K[h][d], V[h][d]}; O: [B*S][2048] bf16.
// Block = (qblock 64 rows, head, batch); 4 waves x 16 q-rows; KVBLK=64.
#define SCALE_ATT 0.08838834764831845f  // 1/sqrt(128)

__global__ __launch_bounds__(256) void attn_kernel(const u16* __restrict__ QKV,
                                                   u16* __restrict__ O) {
  __shared__ alignas(16) u16 Ks[64 * 128];    // swizzled content, linear layout
  __shared__ alignas(16) u16 Vt[128 * 88];    // V^T, padded rows (88 elems)
  __shared__ alignas(16) u16 Ps[4][16 * 88];  // per-wave P strip, padded

  const int tid = threadIdx.x, lane = tid & 63, wave = tid >> 6;
  const int r15 = lane & 15, g = lane >> 4;
  const int qb = blockIdx.x, h = blockIdx.y, b = blockIdx.z;

  const int base = b * 2048 * 6144 + h * 128;
  const u16* Qp = QKV + base;
  const u16* Kp = QKV + base + 2048;
  const u16* Vp = QKV + base + 4096;

  // Q fragments for this wave's 16 rows (held in regs across the kv loop)
  const int qrow = qb * 64 + wave * 16 + r15;
  bf16x8 qf[4];
#pragma unroll
  for (int kc = 0; kc < 4; ++kc)
    qf[kc] = *(const bf16x8*)(Qp + qrow * 6144 + kc * 32 + g * 8);

  // K staging precompute (1024 chunks of 16B; 4 rounds x 4 waves x 64 lanes)
  int koff[4], ksb[4];
#pragma unroll
  for (int i = 0; i < 4; ++i) {
    int c = (i * 4 + wave) * 64 + lane;   // 0..1023
    int row = c >> 4;                      // 16 chunks per 128-elem row
    int q = (c & 15) ^ (row & 7);          // inverse swizzle for source
    koff[i] = row * 6144 + q * 8;
    ksb[i] = (i * 4 + wave) * 1024;
  }
  const int vkv = lane, vd0 = wave * 32;   // V transpose assignment
  const int ksw = r15 & 7;

  f32x4 oacc[8] = {};
  float mrow[4] = {-1e30f, -1e30f, -1e30f, -1e30f};
  float lrow[4] = {0.f, 0.f, 0.f, 0.f};

  for (int kv0 = 0; kv0 < 2048; kv0 += 64) {
    __syncthreads();
    // stage K tile (direct-to-LDS, swizzled source)
#pragma unroll
    for (int i = 0; i < 4; ++i)
      gload_lds16(Kp + kv0 * 6144 + koff[i], (char*)Ks + ksb[i]);
    // stage V^T (reg transpose); thread: kv row = lane, d range = wave*32..+31
    u16 vv[32];
#pragma unroll
    for (int j = 0; j < 4; ++j)
      *(u16x8*)(vv + j * 8) =
          *(const u16x8*)(Vp + (kv0 + vkv) * 6144 + vd0 + j * 8);
#pragma unroll
    for (int j = 0; j < 32; ++j)
      Vt[(vd0 + j) * 88 + vkv] = vv[j];
    __syncthreads();

    // S = Q K^T (16 MFMAs per wave)
    f32x4 sacc[4] = {};
#pragma unroll
    for (int t = 0; t < 4; ++t) {
      const int kvr = t * 16 + r15;
#pragma unroll
      for (int kc = 0; kc < 4; ++kc) {
        bf16x8 kf = *(const bf16x8*)((const char*)Ks + kvr * 256 +
                                     (((kc * 4 + g) ^ ksw) << 4));
        sacc[t] = __builtin_amdgcn_mfma_f32_16x16x32_bf16(qf[kc], kf, sacc[t], 0, 0, 0);
      }
    }

    // online softmax: rows live in (g, reg); cols across r15 lanes and 4 tiles
    float p[4][4], alpha[4];
#pragma unroll
    for (int r = 0; r < 4; ++r) {
      float mx = fmaxf(fmaxf(sacc[0][r], sacc[1][r]),
                       fmaxf(sacc[2][r], sacc[3][r])) * SCALE_ATT;
#pragma unroll
      for (int m = 1; m < 16; m <<= 1) mx = fmaxf(mx, __shfl_xor(mx, m));
      float mn = fmaxf(mrow[r], mx);
      alpha[r] = __expf(mrow[r] - mn);
      float rs = 0.f;
#pragma unroll
      for (int t = 0; t < 4; ++t) {
        p[t][r] = __expf(sacc[t][r] * SCALE_ATT - mn);
        rs += p[t][r];
      }
#pragma unroll
      for (int m = 1; m < 16; m <<= 1) rs += __shfl_xor(rs, m);
      lrow[r] = lrow[r] * alpha[r] + rs;
      mrow[r] = mn;
    }
#pragma unroll
    for (int dt = 0; dt < 8; ++dt)
#pragma unroll
      for (int r = 0; r < 4; ++r) oacc[dt][r] *= alpha[r];

    // P -> per-wave LDS (A-operand layout for PV)
#pragma unroll
    for (int t = 0; t < 4; ++t)
#pragma unroll
      for (int r = 0; r < 4; ++r)
        Ps[wave][(g * 4 + r) * 88 + t * 16 + r15] = f2bf(p[t][r]);

    // O += P V  (16 MFMAs per wave)
    bf16x8 pf[2];
#pragma unroll
    for (int c = 0; c < 2; ++c)
      pf[c] = *(const bf16x8*)((const char*)Ps[wave] + r15 * 176 + c * 64 + g * 16);
#pragma unroll
    for (int dt = 0; dt < 8; ++dt)
#pragma unroll
      for (int c = 0; c < 2; ++c) {
        bf16x8 vf = *(const bf16x8*)((const char*)Vt + (dt * 16 + r15) * 176 +
                                     c * 64 + g * 16);
        oacc[dt] = __builtin_amdgcn_mfma_f32_16x16x32_bf16(pf[c], vf, oacc[dt], 0, 0, 0);
      }
  }

  // epilogue: normalize and store bf16 [b][q][h][d]
  const int qout = qb * 64 + wave * 16 + g * 4;
  u16* Ob = O + (b * 2048 + qout) * 2048 + h * 128;
#pragma unroll
  for (int r = 0; r < 4; ++r) {
    float inv = 1.0f / lrow[r];
#pragma unroll
    for (int dt = 0; dt < 8; ++dt)
      Ob[r * 2048 + dt * 16 + r15] = f2bf(oacc[dt][r] * inv);
  }
}

// ---------------- host ----------------
extern "C" void kernel_launch(void* const* d_in, const int* in_sizes, int n_in,
                              void* d_out, int out_size, void* d_ws, size_t ws_size,
                              hipStream_t stream) {
  const float* x  = (const float*)d_in[0];
  const float* Wq = (const float*)d_in[1];
  const float* Wk = (const float*)d_in[2];
  const float* Wv = (const float*)d_in[3];
  const float* Wo = (const float*)d_in[4];
  const float* bo = (const float*)d_in[5];
  float* out = (float*)d_out;

  char* ws = (char*)d_ws;
  u16* xb    = (u16*)ws;                            // 16 MiB (reused as attn O)
  u16* WqkvT = (u16*)(ws + (size_t)16 * 1024 * 1024);  // 24 MiB [6144][2048]
  u16* WoT   = (u16*)(ws + (size_t)40 * 1024 * 1024);  // 8 MiB  [2048][2048]
  u16* QKV   = (u16*)(ws + (size_t)48 * 1024 * 1024);  // 48 MiB [4096][6144]
  u16* Oattn = xb;

  cast_x_kernel<<<4096, 256, 0, stream>>>(x, xb);
  dim3 tb(32, 8), tg(64, 64);
  transcast<<<tg, tb, 0, stream>>>(Wq, WqkvT, 2048);
  transcast<<<tg, tb, 0, stream>>>(Wk, WqkvT + 2048 * 2048, 2048);
  transcast<<<tg, tb, 0, stream>>>(Wv, WqkvT + 2 * 2048 * 2048, 2048);
  transcast<<<tg, tb, 0, stream>>>(Wo, WoT, 2048);

  // QKV = xb @ [Wq|Wk|Wv]   (M=4096, N=6144, K=2048)
  gemm_bt<0><<<dim3(32, 48), 256, 0, stream>>>(xb, WqkvT, nullptr, QKV, nullptr,
                                               4096, 6144, 2048, 2048, 2048, 6144);
  // attention
  attn_kernel<<<dim3(32, 16, 2), 256, 0, stream>>>(QKV, Oattn);
  // out = O @ Wo + bo       (M=4096, N=2048, K=2048), f32 out
  gemm_bt<1><<<dim3(32, 16), 256, 0, stream>>>(Oattn, WoT, out, nullptr, bo,
                                               4096, 2048, 2048, 2048, 2048, 2048);
}

// Round 2
// 387.084 us; speedup vs baseline: 1.1174x; 1.1174x over previous
//
#include <hip/hip_runtime.h>
#include <hip/hip_bf16.h>

typedef unsigned short u16;
typedef unsigned int   u32;
typedef __bf16 bf16x8 __attribute__((ext_vector_type(8)));
typedef float  f32x4  __attribute__((ext_vector_type(4)));
typedef u16    u16x8  __attribute__((ext_vector_type(8)));
typedef u16    u16x4  __attribute__((ext_vector_type(4)));

#define GAS __attribute__((address_space(1)))
#define LAS __attribute__((address_space(3)))

__device__ __forceinline__ void gload_lds16(const void* g, void* lds) {
  __builtin_amdgcn_global_load_lds((GAS u32*)g, (LAS u32*)lds, 16, 0, 0);
}

__device__ __forceinline__ u16 f2bf(float f) {
  union { float f; u32 u; } v; v.f = f;
  u32 r = v.u + 0x7FFFu + ((v.u >> 16) & 1u);   // round-to-nearest-even
  return (u16)(r >> 16);
}

// ---------------- elementwise cast x: f32 -> bf16 (8 elems/thread) ----------------
__global__ __launch_bounds__(256) void cast_x_kernel(const float* __restrict__ x,
                                                     u16* __restrict__ xb) {
  int i = (blockIdx.x * 256 + threadIdx.x) * 8;
  float4 a = *(const float4*)(x + i);
  float4 b = *(const float4*)(x + i + 4);
  u16x8 o;
  o[0] = f2bf(a.x); o[1] = f2bf(a.y); o[2] = f2bf(a.z); o[3] = f2bf(a.w);
  o[4] = f2bf(b.x); o[5] = f2bf(b.y); o[6] = f2bf(b.z); o[7] = f2bf(b.w);
  *(u16x8*)(xb + i) = o;
}

// ---------------- transpose-cast: W[k][n] f32 -> WT[n][k] bf16 ----------------
__global__ __launch_bounds__(256) void transcast(const float* __restrict__ W,
                                                 u16* __restrict__ WT, int dim) {
  __shared__ float t[32][33];
  int tx = threadIdx.x, ty = threadIdx.y;      // 32 x 8
  int c0 = blockIdx.x * 32, r0 = blockIdx.y * 32;
#pragma unroll
  for (int i = 0; i < 4; ++i)
    t[ty + i * 8][tx] = W[(r0 + ty + i * 8) * dim + c0 + tx];
  __syncthreads();
#pragma unroll
  for (int i = 0; i < 4; ++i)
    WT[(c0 + ty + i * 8) * dim + r0 + tx] = f2bf(t[tx][ty + i * 8]);
}

// ---------------- GEMM: C[M][N] = A[M][K] * B^T (B stored [N][K]) ----------------
template <int OUTF32>
__global__ __launch_bounds__(256) void gemm_bt(
    const u16* __restrict__ A, const u16* __restrict__ B,
    float* __restrict__ Cf, u16* __restrict__ Cb, const float* __restrict__ bias,
    int M, int N, int K, int lda, int ldb, int ldc) {
  __shared__ alignas(16) u16 As[128 * 32];
  __shared__ alignas(16) u16 Bs[128 * 32];
  const int tid = threadIdx.x;
  const int lane = tid & 63, wave = tid >> 6;
  const int wm = wave >> 1, wn = wave & 1;
  const int r15 = lane & 15, g = lane >> 4;
  const int tm = blockIdx.x * 128, tn = blockIdx.y * 128;

  int aoff[2], boff[2], sbase[2];
#pragma unroll
  for (int i = 0; i < 2; ++i) {
    int c = (i * 4 + wave) * 64 + lane;       // 0..511
    int row = c >> 2;
    int q = (c & 3) ^ ((row >> 1) & 3);
    aoff[i] = (tm + row) * lda + q * 8;
    boff[i] = (tn + row) * ldb + q * 8;
    sbase[i] = (i * 4 + wave) * 1024;
  }
  const int sw = (r15 >> 1) & 3;
  int ard[4], brd[4];
#pragma unroll
  for (int t = 0; t < 4; ++t) {
    ard[t] = (wm * 64 + t * 16 + r15) * 64 + ((g ^ sw) << 4);
    brd[t] = (wn * 64 + t * 16 + r15) * 64 + ((g ^ sw) << 4);
  }

  f32x4 acc[4][4] = {};

  for (int k0 = 0; k0 < K; k0 += 32) {
    __syncthreads();
#pragma unroll
    for (int i = 0; i < 2; ++i) {
      gload_lds16(A + aoff[i] + k0, (char*)As + sbase[i]);
      gload_lds16(B + boff[i] + k0, (char*)Bs + sbase[i]);
    }
    __syncthreads();
    bf16x8 af[4], bfr[4];
#pragma unroll
    for (int t = 0; t < 4; ++t) {
      af[t]  = *(const bf16x8*)((const char*)As + ard[t]);
      bfr[t] = *(const bf16x8*)((const char*)Bs + brd[t]);
    }
#pragma unroll
    for (int mi = 0; mi < 4; ++mi)
#pragma unroll
      for (int ni = 0; ni < 4; ++ni)
        acc[mi][ni] = __builtin_amdgcn_mfma_f32_16x16x32_bf16(af[mi], bfr[ni],
                                                              acc[mi][ni], 0, 0, 0);
  }

#pragma unroll
  for (int mi = 0; mi < 4; ++mi)
#pragma unroll
    for (int ni = 0; ni < 4; ++ni)
#pragma unroll
      for (int r = 0; r < 4; ++r) {
        int m = tm + wm * 64 + mi * 16 + g * 4 + r;
        int n = tn + wn * 64 + ni * 16 + r15;
        float v = acc[mi][ni][r];
        if (OUTF32) Cf[m * ldc + n] = v + bias[n];
        else        Cb[m * ldc + n] = f2bf(v);
      }
}

// ---------------- flash attention (both MFMAs swapped; lane-local softmax) ------
// QK:  [B*S][4096] bf16 rows = {Q[h][d], K[h][d]}
// VtG: [2048][4096] bf16 = V^T, row (h*128+d), col (b*2048+s)
// O:   [B*S][2048] bf16
__global__ __launch_bounds__(256) void attn_kernel(const u16* __restrict__ QK,
                                                   const u16* __restrict__ VtG,
                                                   u16* __restrict__ O) {
  __shared__ alignas(16) u16 Ks[64 * 128];   // K tile, swizzled chunks
  __shared__ alignas(16) u16 Vs[128 * 64];   // V^T tile, swizzled chunks

  const int tid = threadIdx.x, lane = tid & 63, wave = tid >> 6;
  const int r15 = lane & 15, g = lane >> 4;
  const int qb = blockIdx.x, h = blockIdx.y, b = blockIdx.z;

  const u16* Qp = QK + (size_t)b * 2048 * 4096 + h * 128;
  const u16* Kp = Qp + 2048;
  const u16* Vp = VtG + (size_t)(h * 128) * 4096 + b * 2048;

  // Q fragments: this lane's q-row is r15 (within the wave's 16-row strip)
  const int qrow = qb * 64 + wave * 16 + r15;
  bf16x8 qf[4];
#pragma unroll
  for (int kc = 0; kc < 4; ++kc)
    qf[kc] = *(const bf16x8*)(Qp + (size_t)qrow * 4096 + kc * 32 + g * 8);

  // staging offsets (16B chunks; inverse-swizzled source, linear LDS dest)
  int koff[4], voff[4], sb[4];
#pragma unroll
  for (int i = 0; i < 4; ++i) {
    int c = (i * 4 + wave) * 64 + lane;        // 0..1023
    int krow = c >> 4, kq = (c & 15) ^ (krow & 7);   // K: 16 chunks/row (128 elems)
    koff[i] = krow * 4096 + kq * 8;
    int vrow = c >> 3, vq = (c & 7) ^ (vrow & 7);    // V: 8 chunks/row (64 elems)
    voff[i] = vrow * 4096 + vq * 8;
    sb[i] = (i * 4 + wave) * 1024;             // bytes
  }
  const int sw = r15 & 7;

  f32x4 oacc[8] = {};
  float m = -1e30f, l = 0.f;
  const float C2 = 0.12753102f;                // (1/sqrt(128)) * log2(e)
  const float THR = 8.0f / C2;                 // defer-max threshold in raw-s units

  for (int kv0 = 0; kv0 < 2048; kv0 += 64) {
    __syncthreads();
#pragma unroll
    for (int i = 0; i < 4; ++i) {
      gload_lds16(Kp + (size_t)kv0 * 4096 + koff[i], (char*)Ks + sb[i]);
      gload_lds16(Vp + kv0 + voff[i], (char*)Vs + sb[i]);
    }
    __syncthreads();

    // S^T[kv][q] = K · Q^T : lane holds kv = t*16 + g*4 + r for q = r15
    f32x4 sacc[4] = {};
#pragma unroll
    for (int t = 0; t < 4; ++t) {
      const int krow = t * 16 + r15;
#pragma unroll
      for (int kc = 0; kc < 4; ++kc) {
        bf16x8 kf = *(const bf16x8*)((const char*)Ks + krow * 256 +
                                     (((kc * 4 + g) ^ sw) << 4));
        sacc[t] = __builtin_amdgcn_mfma_f32_16x16x32_bf16(kf, qf[kc], sacc[t], 0, 0, 0);
      }
    }

    // lane-local online softmax for q-row r15 (redundant across g, harmless)
    float mx = sacc[0][0];
#pragma unroll
    for (int t = 0; t < 4; ++t)
#pragma unroll
      for (int r = 0; r < 4; ++r) mx = fmaxf(mx, sacc[t][r]);
    mx = fmaxf(mx, __shfl_xor(mx, 16));
    mx = fmaxf(mx, __shfl_xor(mx, 32));

    if (!__all(mx - m <= THR)) {               // defer-max: skip rescale when safe
      float mn = fmaxf(m, mx);
      float alpha = exp2f((m - mn) * C2);
#pragma unroll
      for (int dt = 0; dt < 8; ++dt) oacc[dt] *= alpha;
      l *= alpha;
      m = mn;
    }

    float p[4][4], rs = 0.f;
#pragma unroll
    for (int t = 0; t < 4; ++t)
#pragma unroll
      for (int r = 0; r < 4; ++r) {
        p[t][r] = exp2f((sacc[t][r] - m) * C2);
        rs += p[t][r];
      }
    rs += __shfl_xor(rs, 16);
    rs += __shfl_xor(rs, 32);
    l += rs;

    // pack P to bf16 pairs: pk[t][w] covers kv = 16t + 4g + {2w, 2w+1}
    u32 pk[4][2];
#pragma unroll
    for (int t = 0; t < 4; ++t) {
      pk[t][0] = (u32)f2bf(p[t][0]) | ((u32)f2bf(p[t][1]) << 16);
      pk[t][1] = (u32)f2bf(p[t][2]) | ((u32)f2bf(p[t][3]) << 16);
    }
    // assemble PV B-fragments: lane needs P[q=r15][kv = kc2*32 + 8g + 0..7]
    const int L0 = r15 + ((g & 1) << 5);       // source lane for kv run low half
    const int L1 = L0 + 16;                    // +4 offset half
    const bool hi = (g >> 1) & 1;              // t-select: g>=2 uses t+1
    bf16x8 pf[2];
#pragma unroll
    for (int kc2 = 0; kc2 < 2; ++kc2) {
      u32 w0a = __shfl((int)pk[2 * kc2][0], L0), w0b = __shfl((int)pk[2 * kc2 + 1][0], L0);
      u32 w1a = __shfl((int)pk[2 * kc2][1], L0), w1b = __shfl((int)pk[2 * kc2 + 1][1], L0);
      u32 w2a = __shfl((int)pk[2 * kc2][0], L1), w2b = __shfl((int)pk[2 * kc2 + 1][0], L1);
      u32 w3a = __shfl((int)pk[2 * kc2][1], L1), w3b = __shfl((int)pk[2 * kc2 + 1][1], L1);
      union { u32 u[4]; bf16x8 v; } uu;
      uu.u[0] = hi ? w0b : w0a;
      uu.u[1] = hi ? w1b : w1a;
      uu.u[2] = hi ? w2b : w2a;
      uu.u[3] = hi ? w3b : w3a;
      pf[kc2] = uu.v;
    }

    // O^T[d][q] += V^T · P^T : oacc[dt] rows d = dt*16 + g*4 + r, col q = r15
#pragma unroll
    for (int dt = 0; dt < 8; ++dt)
#pragma unroll
      for (int kc2 = 0; kc2 < 2; ++kc2) {
        bf16x8 af = *(const bf16x8*)((const char*)Vs + (dt * 16 + r15) * 128 +
                                     (((kc2 * 4 + g) ^ sw) << 4));
        oacc[dt] = __builtin_amdgcn_mfma_f32_16x16x32_bf16(af, pf[kc2], oacc[dt], 0, 0, 0);
      }
  }

  // epilogue: lane-local normalize; write O[token][h*128 + d], 8B per dt
  const float inv = 1.0f / l;
  u16* Ob = O + ((size_t)(b * 2048 + qrow)) * 2048 + h * 128;
#pragma unroll
  for (int dt = 0; dt < 8; ++dt) {
    u16x4 o4;
#pragma unroll
    for (int r = 0; r < 4; ++r) o4[r] = f2bf(oacc[dt][r] * inv);
    *(u16x4*)(Ob + dt * 16 + g * 4) = o4;
  }
}

// ---------------- host ----------------
extern "C" void kernel_launch(void* const* d_in, const int* in_sizes, int n_in,
                              void* d_out, int out_size, void* d_ws, size_t ws_size,
                              hipStream_t stream) {
  const float* x  = (const float*)d_in[0];
  const float* Wq = (const float*)d_in[1];
  const float* Wk = (const float*)d_in[2];
  const float* Wv = (const float*)d_in[3];
  const float* Wo = (const float*)d_in[4];
  const float* bo = (const float*)d_in[5];
  float* out = (float*)d_out;

  char* ws = (char*)d_ws;
  u16* xb    = (u16*)ws;                               // 16 MiB (reused as attn O)
  u16* WqkvT = (u16*)(ws + (size_t)16 * 1024 * 1024);  // 24 MiB [6144][2048]
  u16* WoT   = (u16*)(ws + (size_t)40 * 1024 * 1024);  // 8 MiB  [2048][2048]
  u16* QK    = (u16*)(ws + (size_t)48 * 1024 * 1024);  // 32 MiB [4096][4096]
  u16* VtG   = (u16*)(ws + (size_t)80 * 1024 * 1024);  // 16 MiB [2048][4096]
  u16* Oattn = xb;

  cast_x_kernel<<<4096, 256, 0, stream>>>(x, xb);
  dim3 tb(32, 8), tg(64, 64);
  transcast<<<tg, tb, 0, stream>>>(Wq, WqkvT, 2048);
  transcast<<<tg, tb, 0, stream>>>(Wk, WqkvT + 2048 * 2048, 2048);
  transcast<<<tg, tb, 0, stream>>>(Wv, WqkvT + 2 * 2048 * 2048, 2048);
  transcast<<<tg, tb, 0, stream>>>(Wo, WoT, 2048);

  // QK = xb @ [Wq|Wk]   (M=4096, N=4096, K=2048)
  gemm_bt<0><<<dim3(32, 32), 256, 0, stream>>>(xb, WqkvT, nullptr, QK, nullptr,
                                               4096, 4096, 2048, 2048, 2048, 4096);
  // V^T = Wv^T @ x^T    (M=2048, N=4096, K=2048) -> [h*128+d][b*2048+s]
  gemm_bt<0><<<dim3(16, 32), 256, 0, stream>>>(WqkvT + (size_t)4096 * 2048, xb,
                                               nullptr, VtG, nullptr,
                                               2048, 4096, 2048, 2048, 2048, 4096);
  // attention
  attn_kernel<<<dim3(32, 16, 2), 256, 0, stream>>>(QK, VtG, Oattn);
  // out = O @ Wo + bo   (M=4096, N=2048, K=2048), f32 out
  gemm_bt<1><<<dim3(32, 16), 256, 0, stream>>>(Oattn, WoT, out, nullptr, bo,
                                               4096, 2048, 2048, 2048, 2048, 2048);
}

// Round 3
// 384.986 us; speedup vs baseline: 1.1235x; 1.0055x over previous
//
#include <hip/hip_runtime.h>
#include <hip/hip_bf16.h>

typedef unsigned short u16;
typedef unsigned int   u32;
typedef __bf16 bf16x8 __attribute__((ext_vector_type(8)));
typedef float  f32x4  __attribute__((ext_vector_type(4)));
typedef u16    u16x8  __attribute__((ext_vector_type(8)));
typedef u16    u16x4  __attribute__((ext_vector_type(4)));

#define GAS __attribute__((address_space(1)))
#define LAS __attribute__((address_space(3)))

__device__ __forceinline__ void gload_lds16(const void* g, void* lds) {
  __builtin_amdgcn_global_load_lds((GAS u32*)g, (LAS u32*)lds, 16, 0, 0);
}

__device__ __forceinline__ u16 f2bf(float f) {
  union { float f; u32 u; } v; v.f = f;
  u32 r = v.u + 0x7FFFu + ((v.u >> 16) & 1u);   // round-to-nearest-even
  return (u16)(r >> 16);
}

__device__ __forceinline__ u32 cvtpk_bf16(float lo, float hi) {
  u32 r;
  asm("v_cvt_pk_bf16_f32 %0, %1, %2" : "=v"(r) : "v"(lo), "v"(hi));
  return r;
}

// ---------------- elementwise cast x: f32 -> bf16 (8 elems/thread) ----------------
__global__ __launch_bounds__(256) void cast_x_kernel(const float* __restrict__ x,
                                                     u16* __restrict__ xb) {
  int i = (blockIdx.x * 256 + threadIdx.x) * 8;
  float4 a = *(const float4*)(x + i);
  float4 b = *(const float4*)(x + i + 4);
  u16x8 o;
  o[0] = f2bf(a.x); o[1] = f2bf(a.y); o[2] = f2bf(a.z); o[3] = f2bf(a.w);
  o[4] = f2bf(b.x); o[5] = f2bf(b.y); o[6] = f2bf(b.z); o[7] = f2bf(b.w);
  *(u16x8*)(xb + i) = o;
}

// ---------------- transpose-cast: W[k][n] f32 -> WT[n][k] bf16 (times scale) ------
__global__ __launch_bounds__(256) void transcast(const float* __restrict__ W,
                                                 u16* __restrict__ WT, int dim,
                                                 float scale) {
  __shared__ float t[32][33];
  int tx = threadIdx.x, ty = threadIdx.y;      // 32 x 8
  int c0 = blockIdx.x * 32, r0 = blockIdx.y * 32;
#pragma unroll
  for (int i = 0; i < 4; ++i)
    t[ty + i * 8][tx] = W[(r0 + ty + i * 8) * dim + c0 + tx];
  __syncthreads();
#pragma unroll
  for (int i = 0; i < 4; ++i)
    WT[(c0 + ty + i * 8) * dim + r0 + tx] = f2bf(t[tx][ty + i * 8] * scale);
}

// ---------------- GEMM: C[M][N] = A[M][K] * B^T (B stored [N][K]) ----------------
template <int OUTF32>
__global__ __launch_bounds__(256) void gemm_bt(
    const u16* __restrict__ A, const u16* __restrict__ B,
    float* __restrict__ Cf, u16* __restrict__ Cb, const float* __restrict__ bias,
    int M, int N, int K, int lda, int ldb, int ldc) {
  __shared__ alignas(16) u16 As[128 * 32];
  __shared__ alignas(16) u16 Bs[128 * 32];
  const int tid = threadIdx.x;
  const int lane = tid & 63, wave = tid >> 6;
  const int wm = wave >> 1, wn = wave & 1;
  const int r15 = lane & 15, g = lane >> 4;
  const int tm = blockIdx.x * 128, tn = blockIdx.y * 128;

  int aoff[2], boff[2], sbase[2];
#pragma unroll
  for (int i = 0; i < 2; ++i) {
    int c = (i * 4 + wave) * 64 + lane;       // 0..511
    int row = c >> 2;
    int q = (c & 3) ^ ((row >> 1) & 3);
    aoff[i] = (tm + row) * lda + q * 8;
    boff[i] = (tn + row) * ldb + q * 8;
    sbase[i] = (i * 4 + wave) * 1024;
  }
  const int sw = (r15 >> 1) & 3;
  int ard[4], brd[4];
#pragma unroll
  for (int t = 0; t < 4; ++t) {
    ard[t] = (wm * 64 + t * 16 + r15) * 64 + ((g ^ sw) << 4);
    brd[t] = (wn * 64 + t * 16 + r15) * 64 + ((g ^ sw) << 4);
  }

  f32x4 acc[4][4] = {};

  for (int k0 = 0; k0 < K; k0 += 32) {
    __syncthreads();
#pragma unroll
    for (int i = 0; i < 2; ++i) {
      gload_lds16(A + aoff[i] + k0, (char*)As + sbase[i]);
      gload_lds16(B + boff[i] + k0, (char*)Bs + sbase[i]);
    }
    __syncthreads();
    bf16x8 af[4], bfr[4];
#pragma unroll
    for (int t = 0; t < 4; ++t) {
      af[t]  = *(const bf16x8*)((const char*)As + ard[t]);
      bfr[t] = *(const bf16x8*)((const char*)Bs + brd[t]);
    }
#pragma unroll
    for (int mi = 0; mi < 4; ++mi)
#pragma unroll
      for (int ni = 0; ni < 4; ++ni)
        acc[mi][ni] = __builtin_amdgcn_mfma_f32_16x16x32_bf16(af[mi], bfr[ni],
                                                              acc[mi][ni], 0, 0, 0);
  }

#pragma unroll
  for (int mi = 0; mi < 4; ++mi)
#pragma unroll
    for (int ni = 0; ni < 4; ++ni)
#pragma unroll
      for (int r = 0; r < 4; ++r) {
        int m = tm + wm * 64 + mi * 16 + g * 4 + r;
        int n = tn + wn * 64 + ni * 16 + r15;
        float v = acc[mi][ni][r];
        if (OUTF32) Cf[m * ldc + n] = v + bias[n];
        else        Cb[m * ldc + n] = f2bf(v);
      }
}

// ---------------- flash attention (dbuf pipeline; swapped MFMAs; lane-local SM) ---
// QK:  [B*S][4096] bf16 rows = {Q[h][d], K_scaled[h][d]}  (K pre-scaled by C2)
// VtG: [2048][4096] bf16 = V^T, row (h*128+d), col (b*2048+s)
// O:   [B*S][2048] bf16
__global__ __launch_bounds__(256) void attn_kernel(const u16* __restrict__ QK,
                                                   const u16* __restrict__ VtG,
                                                   u16* __restrict__ O) {
  __shared__ alignas(16) u16 Ks[2][64 * 128];   // K tiles, swizzled chunks
  __shared__ alignas(16) u16 Vs[2][128 * 64];   // V^T tiles, swizzled chunks

  const int tid = threadIdx.x, lane = tid & 63, wave = tid >> 6;
  const int r15 = lane & 15, g = lane >> 4;
  const int qb = blockIdx.x, h = blockIdx.y, b = blockIdx.z;

  const u16* Qp = QK + (size_t)b * 2048 * 4096 + h * 128;
  const u16* Kp = Qp + 2048;
  const u16* Vp = VtG + (size_t)(h * 128) * 4096 + b * 2048;

  // Q fragments: this lane's q-row is r15 (within the wave's 16-row strip)
  const int qrow = qb * 64 + wave * 16 + r15;
  bf16x8 qf[4];
#pragma unroll
  for (int kc = 0; kc < 4; ++kc)
    qf[kc] = *(const bf16x8*)(Qp + (size_t)qrow * 4096 + kc * 32 + g * 8);

  // staging offsets (16B chunks; inverse-swizzled source, linear LDS dest)
  int koff[4], voff[4], sb[4];
#pragma unroll
  for (int i = 0; i < 4; ++i) {
    int c = (i * 4 + wave) * 64 + lane;        // 0..1023
    int krow = c >> 4, kq = (c & 15) ^ (krow & 7);   // K: 16 chunks/row (128 elems)
    koff[i] = krow * 4096 + kq * 8;
    int vrow = c >> 3, vq = (c & 7) ^ (vrow & 7);    // V: 8 chunks/row (64 elems)
    voff[i] = vrow * 4096 + vq * 8;
    sb[i] = (i * 4 + wave) * 1024;             // bytes
  }
  const int sw = r15 & 7;

  f32x4 oacc[8] = {};
  float m = -1e30f, l = 0.f;
  const float THR = 8.0f;                      // defer-max threshold (log2 domain)

  // prologue: stage tile 0 into buffer 0
#pragma unroll
  for (int i = 0; i < 4; ++i) {
    gload_lds16(Kp + koff[i], (char*)Ks[0] + sb[i]);
    gload_lds16(Vp + voff[i], (char*)Vs[0] + sb[i]);
  }
  __syncthreads();

  for (int t = 0; t < 32; ++t) {
    const int cur = t & 1;
    // issue next tile's stage into the other buffer (overlaps with compute below)
    if (t < 31) {
      const int kv0n = (t + 1) * 64;
#pragma unroll
      for (int i = 0; i < 4; ++i) {
        gload_lds16(Kp + (size_t)kv0n * 4096 + koff[i], (char*)Ks[cur ^ 1] + sb[i]);
        gload_lds16(Vp + kv0n + voff[i], (char*)Vs[cur ^ 1] + sb[i]);
      }
    }

    // S^T[kv][q] = K_scaled · Q^T : lane holds kv = t*16 + g*4 + r for q = r15
    f32x4 sacc[4] = {};
#pragma unroll
    for (int tt = 0; tt < 4; ++tt) {
      const int krow = tt * 16 + r15;
#pragma unroll
      for (int kc = 0; kc < 4; ++kc) {
        bf16x8 kf = *(const bf16x8*)((const char*)Ks[cur] + krow * 256 +
                                     (((kc * 4 + g) ^ sw) << 4));
        sacc[tt] = __builtin_amdgcn_mfma_f32_16x16x32_bf16(kf, qf[kc], sacc[tt], 0, 0, 0);
      }
    }

    // lane-local online softmax (log2 domain; scale folded into K)
    float mx = fmaxf(fmaxf(sacc[0][0], sacc[0][1]), fmaxf(sacc[0][2], sacc[0][3]));
#pragma unroll
    for (int tt = 1; tt < 4; ++tt)
#pragma unroll
      for (int r = 0; r < 4; ++r) mx = fmaxf(mx, sacc[tt][r]);
    mx = fmaxf(mx, __shfl_xor(mx, 16));
    mx = fmaxf(mx, __shfl_xor(mx, 32));

    if (!__all(mx - m <= THR)) {               // defer-max: skip rescale when safe
      float mn = fmaxf(m, mx);
      float alpha = exp2f(m - mn);
#pragma unroll
      for (int dt = 0; dt < 8; ++dt) oacc[dt] *= alpha;
      l *= alpha;
      m = mn;
    }

    float p[4][4], rs = 0.f;
#pragma unroll
    for (int tt = 0; tt < 4; ++tt)
#pragma unroll
      for (int r = 0; r < 4; ++r) {
        p[tt][r] = exp2f(sacc[tt][r] - m);
        rs += p[tt][r];
      }
    rs += __shfl_xor(rs, 16);
    rs += __shfl_xor(rs, 32);
    l += rs;

    // pack P to bf16 pairs: pk[tt][w] covers kv = 16tt + 4g + {2w, 2w+1}
    u32 pk[4][2];
#pragma unroll
    for (int tt = 0; tt < 4; ++tt) {
      pk[tt][0] = cvtpk_bf16(p[tt][0], p[tt][1]);
      pk[tt][1] = cvtpk_bf16(p[tt][2], p[tt][3]);
    }
    // assemble PV B-fragments: lane needs P[q=r15][kv = kc2*32 + 8g + 0..7]
    const int L0 = r15 + ((g & 1) << 5);       // source lane for kv run low half
    const int L1 = L0 + 16;                    // +4 offset half
    const bool hi = (g >> 1) & 1;              // t-select: g>=2 uses t+1
    bf16x8 pf[2];
#pragma unroll
    for (int kc2 = 0; kc2 < 2; ++kc2) {
      u32 w0a = __shfl((int)pk[2 * kc2][0], L0), w0b = __shfl((int)pk[2 * kc2 + 1][0], L0);
      u32 w1a = __shfl((int)pk[2 * kc2][1], L0), w1b = __shfl((int)pk[2 * kc2 + 1][1], L0);
      u32 w2a = __shfl((int)pk[2 * kc2][0], L1), w2b = __shfl((int)pk[2 * kc2 + 1][0], L1);
      u32 w3a = __shfl((int)pk[2 * kc2][1], L1), w3b = __shfl((int)pk[2 * kc2 + 1][1], L1);
      union { u32 u[4]; bf16x8 v; } uu;
      uu.u[0] = hi ? w0b : w0a;
      uu.u[1] = hi ? w1b : w1a;
      uu.u[2] = hi ? w2b : w2a;
      uu.u[3] = hi ? w3b : w3a;
      pf[kc2] = uu.v;
    }

    // O^T[d][q] += V^T · P^T : oacc[dt] rows d = dt*16 + g*4 + r, col q = r15
#pragma unroll
    for (int dt = 0; dt < 8; ++dt)
#pragma unroll
      for (int kc2 = 0; kc2 < 2; ++kc2) {
        bf16x8 af = *(const bf16x8*)((const char*)Vs[cur] + (dt * 16 + r15) * 128 +
                                     (((kc2 * 4 + g) ^ sw) << 4));
        oacc[dt] = __builtin_amdgcn_mfma_f32_16x16x32_bf16(af, pf[kc2], oacc[dt], 0, 0, 0);
      }

    __syncthreads();   // fences buf[cur] reads; next iter stages into buf[cur]
  }

  // epilogue: lane-local normalize; write O[token][h*128 + d], 8B per dt
  const float inv = 1.0f / l;
  u16* Ob = O + ((size_t)(b * 2048 + qrow)) * 2048 + h * 128;
#pragma unroll
  for (int dt = 0; dt < 8; ++dt) {
    u16x4 o4;
#pragma unroll
    for (int r = 0; r < 4; ++r) o4[r] = f2bf(oacc[dt][r] * inv);
    *(u16x4*)(Ob + dt * 16 + g * 4) = o4;
  }
}

// ---------------- host ----------------
extern "C" void kernel_launch(void* const* d_in, const int* in_sizes, int n_in,
                              void* d_out, int out_size, void* d_ws, size_t ws_size,
                              hipStream_t stream) {
  const float* x  = (const float*)d_in[0];
  const float* Wq = (const float*)d_in[1];
  const float* Wk = (const float*)d_in[2];
  const float* Wv = (const float*)d_in[3];
  const float* Wo = (const float*)d_in[4];
  const float* bo = (const float*)d_in[5];
  float* out = (float*)d_out;

  char* ws = (char*)d_ws;
  u16* xb    = (u16*)ws;                               // 16 MiB (reused as attn O)
  u16* WqkvT = (u16*)(ws + (size_t)16 * 1024 * 1024);  // 24 MiB [6144][2048]
  u16* WoT   = (u16*)(ws + (size_t)40 * 1024 * 1024);  // 8 MiB  [2048][2048]
  u16* QK    = (u16*)(ws + (size_t)48 * 1024 * 1024);  // 32 MiB [4096][4096]
  u16* VtG   = (u16*)(ws + (size_t)80 * 1024 * 1024);  // 16 MiB [2048][4096]
  u16* Oattn = xb;

  const float C2 = 0.12753102f;   // (1/sqrt(128)) * log2(e), folded into Wk

  cast_x_kernel<<<4096, 256, 0, stream>>>(x, xb);
  dim3 tb(32, 8), tg(64, 64);
  transcast<<<tg, tb, 0, stream>>>(Wq, WqkvT, 2048, 1.0f);
  transcast<<<tg, tb, 0, stream>>>(Wk, WqkvT + 2048 * 2048, 2048, C2);
  transcast<<<tg, tb, 0, stream>>>(Wv, WqkvT + 2 * 2048 * 2048, 2048, 1.0f);
  transcast<<<tg, tb, 0, stream>>>(Wo, WoT, 2048, 1.0f);

  // QK = xb @ [Wq|Wk_scaled]   (M=4096, N=4096, K=2048)
  gemm_bt<0><<<dim3(32, 32), 256, 0, stream>>>(xb, WqkvT, nullptr, QK, nullptr,
                                               4096, 4096, 2048, 2048, 2048, 4096);
  // V^T = Wv^T @ x^T    (M=2048, N=4096, K=2048) -> [h*128+d][b*2048+s]
  gemm_bt<0><<<dim3(16, 32), 256, 0, stream>>>(WqkvT + (size_t)4096 * 2048, xb,
                                               nullptr, VtG, nullptr,
                                               2048, 4096, 2048, 2048, 2048, 4096);
  // attention
  attn_kernel<<<dim3(32, 16, 2), 256, 0, stream>>>(QK, VtG, Oattn);
  // out = O @ Wo + bo   (M=4096, N=2048, K=2048), f32 out
  gemm_bt<1><<<dim3(32, 16), 256, 0, stream>>>(Oattn, WoT, out, nullptr, bo,
                                               4096, 2048, 2048, 2048, 2048, 2048);
}

// Round 4
// 366.231 us; speedup vs baseline: 1.1810x; 1.0512x over previous
//
#include <hip/hip_runtime.h>
#include <hip/hip_bf16.h>

typedef unsigned short u16;
typedef unsigned int   u32;
typedef __bf16 bf16x8 __attribute__((ext_vector_type(8)));
typedef float  f32x4  __attribute__((ext_vector_type(4)));
typedef u16    u16x8  __attribute__((ext_vector_type(8)));
typedef u16    u16x4  __attribute__((ext_vector_type(4)));

#define GAS __attribute__((address_space(1)))
#define LAS __attribute__((address_space(3)))

__device__ __forceinline__ void gload_lds16(const void* g, void* lds) {
  __builtin_amdgcn_global_load_lds((GAS u32*)g, (LAS u32*)lds, 16, 0, 0);
}

__device__ __forceinline__ u16 f2bf(float f) {
  union { float f; u32 u; } v; v.f = f;
  u32 r = v.u + 0x7FFFu + ((v.u >> 16) & 1u);   // round-to-nearest-even
  return (u16)(r >> 16);
}

__device__ __forceinline__ u32 cvtpk_bf16(float lo, float hi) {
  u32 r;
  asm("v_cvt_pk_bf16_f32 %0, %1, %2" : "=v"(r) : "v"(lo), "v"(hi));
  return r;
}

// ---------------- elementwise cast x: f32 -> bf16 (8 elems/thread) ----------------
__global__ __launch_bounds__(256) void cast_x_kernel(const float* __restrict__ x,
                                                     u16* __restrict__ xb) {
  int i = (blockIdx.x * 256 + threadIdx.x) * 8;
  float4 a = *(const float4*)(x + i);
  float4 b = *(const float4*)(x + i + 4);
  u16x8 o;
  o[0] = f2bf(a.x); o[1] = f2bf(a.y); o[2] = f2bf(a.z); o[3] = f2bf(a.w);
  o[4] = f2bf(b.x); o[5] = f2bf(b.y); o[6] = f2bf(b.z); o[7] = f2bf(b.w);
  *(u16x8*)(xb + i) = o;
}

// ---------------- transpose-cast: W[k][n] f32 -> WT[n][k] bf16 (times scale) ------
__global__ __launch_bounds__(256) void transcast(const float* __restrict__ W,
                                                 u16* __restrict__ WT, int dim,
                                                 float scale) {
  __shared__ float t[32][33];
  int tx = threadIdx.x, ty = threadIdx.y;      // 32 x 8
  int c0 = blockIdx.x * 32, r0 = blockIdx.y * 32;
#pragma unroll
  for (int i = 0; i < 4; ++i)
    t[ty + i * 8][tx] = W[(r0 + ty + i * 8) * dim + c0 + tx];
  __syncthreads();
#pragma unroll
  for (int i = 0; i < 4; ++i)
    WT[(c0 + ty + i * 8) * dim + r0 + tx] = f2bf(t[tx][ty + i * 8] * scale);
}

// ---------------- GEMM: C[M][N] = A[M][K] * B^T (B stored [N][K]) ----------------
template <int OUTF32>
__global__ __launch_bounds__(256) void gemm_bt(
    const u16* __restrict__ A, const u16* __restrict__ B,
    float* __restrict__ Cf, u16* __restrict__ Cb, const float* __restrict__ bias,
    int M, int N, int K, int lda, int ldb, int ldc) {
  __shared__ alignas(16) u16 As[128 * 32];
  __shared__ alignas(16) u16 Bs[128 * 32];
  const int tid = threadIdx.x;
  const int lane = tid & 63, wave = tid >> 6;
  const int wm = wave >> 1, wn = wave & 1;
  const int r15 = lane & 15, g = lane >> 4;
  const int tm = blockIdx.x * 128, tn = blockIdx.y * 128;

  int aoff[2], boff[2], sbase[2];
#pragma unroll
  for (int i = 0; i < 2; ++i) {
    int c = (i * 4 + wave) * 64 + lane;       // 0..511
    int row = c >> 2;
    int q = (c & 3) ^ ((row >> 1) & 3);
    aoff[i] = (tm + row) * lda + q * 8;
    boff[i] = (tn + row) * ldb + q * 8;
    sbase[i] = (i * 4 + wave) * 1024;
  }
  const int sw = (r15 >> 1) & 3;
  int ard[4], brd[4];
#pragma unroll
  for (int t = 0; t < 4; ++t) {
    ard[t] = (wm * 64 + t * 16 + r15) * 64 + ((g ^ sw) << 4);
    brd[t] = (wn * 64 + t * 16 + r15) * 64 + ((g ^ sw) << 4);
  }

  f32x4 acc[4][4] = {};

  for (int k0 = 0; k0 < K; k0 += 32) {
    __syncthreads();
#pragma unroll
    for (int i = 0; i < 2; ++i) {
      gload_lds16(A + aoff[i] + k0, (char*)As + sbase[i]);
      gload_lds16(B + boff[i] + k0, (char*)Bs + sbase[i]);
    }
    __syncthreads();
    bf16x8 af[4], bfr[4];
#pragma unroll
    for (int t = 0; t < 4; ++t) {
      af[t]  = *(const bf16x8*)((const char*)As + ard[t]);
      bfr[t] = *(const bf16x8*)((const char*)Bs + brd[t]);
    }
#pragma unroll
    for (int mi = 0; mi < 4; ++mi)
#pragma unroll
      for (int ni = 0; ni < 4; ++ni)
        acc[mi][ni] = __builtin_amdgcn_mfma_f32_16x16x32_bf16(af[mi], bfr[ni],
                                                              acc[mi][ni], 0, 0, 0);
  }

#pragma unroll
  for (int mi = 0; mi < 4; ++mi)
#pragma unroll
    for (int ni = 0; ni < 4; ++ni)
#pragma unroll
      for (int r = 0; r < 4; ++r) {
        int m = tm + wm * 64 + mi * 16 + g * 4 + r;
        int n = tn + wn * 64 + ni * 16 + r15;
        float v = acc[mi][ni][r];
        if (OUTF32) Cf[m * ldc + n] = v + bias[n];
        else        Cb[m * ldc + n] = f2bf(v);
      }
}

// ---------------- flash attention (counted-vmcnt pipeline; raw barriers) ----------
// QK:  [B*S][4096] bf16 rows = {Q[h][d], K_scaled[h][d]}  (K pre-scaled by C2)
// VtG: [2048][4096] bf16 = V^T, row (h*128+d), col (b*2048+s)
// O:   [B*S][2048] bf16
__global__ __launch_bounds__(256) void attn_kernel(const u16* __restrict__ QK,
                                                   const u16* __restrict__ VtG,
                                                   u16* __restrict__ O) {
  __shared__ alignas(16) u16 Ks[2][64 * 128];   // K tiles, swizzled chunks
  __shared__ alignas(16) u16 Vs[2][128 * 64];   // V^T tiles, swizzled chunks

  const int tid = threadIdx.x, lane = tid & 63, wave = tid >> 6;
  const int r15 = lane & 15, g = lane >> 4;
  const int qb = blockIdx.x, h = blockIdx.y, b = blockIdx.z;

  const u16* Qp = QK + (size_t)b * 2048 * 4096 + h * 128;
  const u16* Kp = Qp + 2048;
  const u16* Vp = VtG + (size_t)(h * 128) * 4096 + b * 2048;

  // Q fragments: this lane's q-row is r15 (within the wave's 16-row strip)
  const int qrow = qb * 64 + wave * 16 + r15;
  bf16x8 qf[4];
#pragma unroll
  for (int kc = 0; kc < 4; ++kc)
    qf[kc] = *(const bf16x8*)(Qp + (size_t)qrow * 4096 + kc * 32 + g * 8);
  // pin Q loads: keeps the vmcnt bookkeeping below exact
  asm volatile("s_waitcnt vmcnt(0)" ::: "memory");

  // staging offsets (16B chunks; inverse-swizzled source, linear LDS dest)
  int koff[4], voff[4], sb[4];
#pragma unroll
  for (int i = 0; i < 4; ++i) {
    int c = (i * 4 + wave) * 64 + lane;        // 0..1023
    int krow = c >> 4, kq = (c & 15) ^ (krow & 7);   // K: 16 chunks/row (128 elems)
    koff[i] = krow * 4096 + kq * 8;
    int vrow = c >> 3, vq = (c & 7) ^ (vrow & 7);    // V: 8 chunks/row (64 elems)
    voff[i] = vrow * 4096 + vq * 8;
    sb[i] = (i * 4 + wave) * 1024;             // bytes
  }
  const int sw = r15 & 7;

  f32x4 oacc[8] = {};
  float m = -1e30f, l = 0.f;
  const float THR = 8.0f;                      // defer-max threshold (log2 domain)

  // prologue: stage tile 0 into buffer 0 (8 loads in flight)
#pragma unroll
  for (int i = 0; i < 4; ++i) {
    gload_lds16(Kp + koff[i], (char*)Ks[0] + sb[i]);
    gload_lds16(Vp + voff[i], (char*)Vs[0] + sb[i]);
  }

  auto compute_tile = [&](int cur) {
    // S^T[kv][q] = K_scaled · Q^T : lane holds kv = tt*16 + g*4 + r for q = r15
    f32x4 sacc[4] = {};
    __builtin_amdgcn_s_setprio(1);
#pragma unroll
    for (int tt = 0; tt < 4; ++tt) {
      const int krow = tt * 16 + r15;
#pragma unroll
      for (int kc = 0; kc < 4; ++kc) {
        bf16x8 kf = *(const bf16x8*)((const char*)Ks[cur] + krow * 256 +
                                     (((kc * 4 + g) ^ sw) << 4));
        sacc[tt] = __builtin_amdgcn_mfma_f32_16x16x32_bf16(kf, qf[kc], sacc[tt], 0, 0, 0);
      }
    }
    __builtin_amdgcn_s_setprio(0);

    // lane-local online softmax (log2 domain; scale folded into K)
    float mx = fmaxf(fmaxf(sacc[0][0], sacc[0][1]), fmaxf(sacc[0][2], sacc[0][3]));
#pragma unroll
    for (int tt = 1; tt < 4; ++tt)
#pragma unroll
      for (int r = 0; r < 4; ++r) mx = fmaxf(mx, sacc[tt][r]);
    mx = fmaxf(mx, __shfl_xor(mx, 16));
    mx = fmaxf(mx, __shfl_xor(mx, 32));

    if (!__all(mx - m <= THR)) {               // defer-max: skip rescale when safe
      float mn = fmaxf(m, mx);
      float alpha = __builtin_amdgcn_exp2f(m - mn);
#pragma unroll
      for (int dt = 0; dt < 8; ++dt) oacc[dt] *= alpha;
      l *= alpha;
      m = mn;
    }

    float p[4][4], rs = 0.f;
#pragma unroll
    for (int tt = 0; tt < 4; ++tt)
#pragma unroll
      for (int r = 0; r < 4; ++r) {
        p[tt][r] = __builtin_amdgcn_exp2f(sacc[tt][r] - m);
        rs += p[tt][r];
      }
    rs += __shfl_xor(rs, 16);
    rs += __shfl_xor(rs, 32);
    l += rs;

    // pack P to bf16 pairs: pk[tt][w] covers kv = 16tt + 4g + {2w, 2w+1}
    u32 pk[4][2];
#pragma unroll
    for (int tt = 0; tt < 4; ++tt) {
      pk[tt][0] = cvtpk_bf16(p[tt][0], p[tt][1]);
      pk[tt][1] = cvtpk_bf16(p[tt][2], p[tt][3]);
    }
    // assemble PV B-fragments: lane needs P[q=r15][kv = kc2*32 + 8g + 0..7]
    const int L0 = r15 + ((g & 1) << 5);       // source lane for kv run low half
    const int L1 = L0 + 16;                    // +4 offset half
    const bool hi = (g >> 1) & 1;              // t-select: g>=2 uses t+1
    bf16x8 pf[2];
#pragma unroll
    for (int kc2 = 0; kc2 < 2; ++kc2) {
      u32 w0a = __shfl((int)pk[2 * kc2][0], L0), w0b = __shfl((int)pk[2 * kc2 + 1][0], L0);
      u32 w1a = __shfl((int)pk[2 * kc2][1], L0), w1b = __shfl((int)pk[2 * kc2 + 1][1], L0);
      u32 w2a = __shfl((int)pk[2 * kc2][0], L1), w2b = __shfl((int)pk[2 * kc2 + 1][0], L1);
      u32 w3a = __shfl((int)pk[2 * kc2][1], L1), w3b = __shfl((int)pk[2 * kc2 + 1][1], L1);
      union { u32 u[4]; bf16x8 v; } uu;
      uu.u[0] = hi ? w0b : w0a;
      uu.u[1] = hi ? w1b : w1a;
      uu.u[2] = hi ? w2b : w2a;
      uu.u[3] = hi ? w3b : w3a;
      pf[kc2] = uu.v;
    }

    // O^T[d][q] += V^T · P^T : oacc[dt] rows d = dt*16 + g*4 + r, col q = r15
    __builtin_amdgcn_s_setprio(1);
#pragma unroll
    for (int dt = 0; dt < 8; ++dt)
#pragma unroll
      for (int kc2 = 0; kc2 < 2; ++kc2) {
        bf16x8 af = *(const bf16x8*)((const char*)Vs[cur] + (dt * 16 + r15) * 128 +
                                     (((kc2 * 4 + g) ^ sw) << 4));
        oacc[dt] = __builtin_amdgcn_mfma_f32_16x16x32_bf16(af, pf[kc2], oacc[dt], 0, 0, 0);
      }
    __builtin_amdgcn_s_setprio(0);
  };

  for (int t = 0; t < 31; ++t) {
    const int cur = t & 1;
    // issue next tile's stage into the other buffer (stays in flight across barrier)
    const size_t kv0n = (size_t)(t + 1) * 64;
#pragma unroll
    for (int i = 0; i < 4; ++i) {
      gload_lds16(Kp + kv0n * 4096 + koff[i], (char*)Ks[cur ^ 1] + sb[i]);
      gload_lds16(Vp + kv0n + voff[i], (char*)Vs[cur ^ 1] + sb[i]);
    }
    // wait only for tile t's 8 loads (tile t+1's 8 remain in flight)
    asm volatile("s_waitcnt vmcnt(8)" ::: "memory");
    __builtin_amdgcn_s_barrier();              // publish tile t to all waves
    __builtin_amdgcn_sched_barrier(0);         // no ds_read hoisting above this
    compute_tile(cur);
    __builtin_amdgcn_s_barrier();              // all waves done reading buf[cur]
  }
  // final tile (31): nothing left to prefetch
  asm volatile("s_waitcnt vmcnt(0)" ::: "memory");
  __builtin_amdgcn_s_barrier();
  __builtin_amdgcn_sched_barrier(0);
  compute_tile(1);

  // epilogue: lane-local normalize; write O[token][h*128 + d], 8B per dt
  const float inv = 1.0f / l;
  u16* Ob = O + ((size_t)(b * 2048 + qrow)) * 2048 + h * 128;
#pragma unroll
  for (int dt = 0; dt < 8; ++dt) {
    u16x4 o4;
#pragma unroll
    for (int r = 0; r < 4; ++r) o4[r] = f2bf(oacc[dt][r] * inv);
    *(u16x4*)(Ob + dt * 16 + g * 4) = o4;
  }
}

// ---------------- host ----------------
extern "C" void kernel_launch(void* const* d_in, const int* in_sizes, int n_in,
                              void* d_out, int out_size, void* d_ws, size_t ws_size,
                              hipStream_t stream) {
  const float* x  = (const float*)d_in[0];
  const float* Wq = (const float*)d_in[1];
  const float* Wk = (const float*)d_in[2];
  const float* Wv = (const float*)d_in[3];
  const float* Wo = (const float*)d_in[4];
  const float* bo = (const float*)d_in[5];
  float* out = (float*)d_out;

  char* ws = (char*)d_ws;
  u16* xb    = (u16*)ws;                               // 16 MiB (reused as attn O)
  u16* WqkvT = (u16*)(ws + (size_t)16 * 1024 * 1024);  // 24 MiB [6144][2048]
  u16* WoT   = (u16*)(ws + (size_t)40 * 1024 * 1024);  // 8 MiB  [2048][2048]
  u16* QK    = (u16*)(ws + (size_t)48 * 1024 * 1024);  // 32 MiB [4096][4096]
  u16* VtG   = (u16*)(ws + (size_t)80 * 1024 * 1024);  // 16 MiB [2048][4096]
  u16* Oattn = xb;

  const float C2 = 0.12753102f;   // (1/sqrt(128)) * log2(e), folded into Wk

  cast_x_kernel<<<4096, 256, 0, stream>>>(x, xb);
  dim3 tb(32, 8), tg(64, 64);
  transcast<<<tg, tb, 0, stream>>>(Wq, WqkvT, 2048, 1.0f);
  transcast<<<tg, tb, 0, stream>>>(Wk, WqkvT + 2048 * 2048, 2048, C2);
  transcast<<<tg, tb, 0, stream>>>(Wv, WqkvT + 2 * 2048 * 2048, 2048, 1.0f);
  transcast<<<tg, tb, 0, stream>>>(Wo, WoT, 2048, 1.0f);

  // QK = xb @ [Wq|Wk_scaled]   (M=4096, N=4096, K=2048)
  gemm_bt<0><<<dim3(32, 32), 256, 0, stream>>>(xb, WqkvT, nullptr, QK, nullptr,
                                               4096, 4096, 2048, 2048, 2048, 4096);
  // V^T = Wv^T @ x^T    (M=2048, N=4096, K=2048) -> [h*128+d][b*2048+s]
  gemm_bt<0><<<dim3(16, 32), 256, 0, stream>>>(WqkvT + (size_t)4096 * 2048, xb,
                                               nullptr, VtG, nullptr,
                                               2048, 4096, 2048, 2048, 2048, 4096);
  // attention
  attn_kernel<<<dim3(32, 16, 2), 256, 0, stream>>>(QK, VtG, Oattn);
  // out = O @ Wo + bo   (M=4096, N=2048, K=2048), f32 out
  gemm_bt<1><<<dim3(32, 16), 256, 0, stream>>>(Oattn, WoT, out, nullptr, bo,
                                               4096, 2048, 2048, 2048, 2048, 2048);
}